// Round 3
// baseline (509.909 us; speedup 1.0000x reference)
//
#include <hip/hip_runtime.h>
#include <stdint.h>

typedef unsigned short u16;
typedef __attribute__((ext_vector_type(8))) short bf16x8;
typedef __attribute__((ext_vector_type(4))) float f32x4;

#define MFMA(a,b,c) __builtin_amdgcn_mfma_f32_16x16x32_bf16((a),(b),(c),0,0,0)

static constexpr int S  = 4096;
static constexpr int D  = 768;
static constexpr int H  = 12;
static constexpr int HD = 64;

// float -> bf16 round-nearest-even
__device__ __forceinline__ u16 f2b(float f){
  union { float f; unsigned u; } v; v.f = f;
  unsigned r = (v.u + 0x7fffu + ((v.u >> 16) & 1u)) >> 16;
  return (u16)r;
}

// pack 2 floats -> 2 bf16 (truncation) in ONE v_perm_b32
__device__ __forceinline__ unsigned pack_bf16_trunc(float a, float b){
  return __builtin_amdgcn_perm(__float_as_uint(b), __float_as_uint(a), 0x07060302u);
}

// ---------------- cast fp32 -> bf16, 4 elems/thread ----------------
__global__ void castk(const float* __restrict__ s, u16* __restrict__ d, int n4){
  int i = blockIdx.x * 256 + threadIdx.x;
  if (i >= n4) return;
  float4 v = ((const float4*)s)[i];
  uint2 o;
  o.x = (unsigned)f2b(v.x) | ((unsigned)f2b(v.y) << 16);
  o.y = (unsigned)f2b(v.z) | ((unsigned)f2b(v.w) << 16);
  ((uint2*)d)[i] = o;
}

// ---------------- QKV GEMM: [8192,768] x Wt[768,768] -> Q/K ([b][h][s][hd]) or Vt ([b][h][hd][s])
// Q is pre-scaled by 0.125*log2(e) so attention softmax can use raw exp2.
__global__ __launch_bounds__(256, 2) void qkv_gemm(
    const u16* __restrict__ xb, const u16* __restrict__ wq, const u16* __restrict__ wk,
    const u16* __restrict__ wv, u16* __restrict__ Qb, u16* __restrict__ Kb, u16* __restrict__ Vt)
{
  __shared__ __align__(16) u16 As[128 * 40];
  __shared__ __align__(16) u16 Bs[128 * 40];
  const int t = threadIdx.x;
  const int mblk = blockIdx.x, nblk = blockIdx.y, z = blockIdx.z;
  const u16* W = (z == 0) ? wq : (z == 1) ? wk : wv;
  const int w = t >> 6, lane = t & 63, quad = lane >> 4, l16 = lane & 15;
  const int wr = w >> 1, wc = w & 1;

  f32x4 acc[4][4];
  #pragma unroll
  for (int i = 0; i < 4; i++)
    #pragma unroll
    for (int j = 0; j < 4; j++) acc[i][j] = (f32x4){0.f, 0.f, 0.f, 0.f};

  const int row0 = t >> 2;
  const int kc   = (t & 3) * 8;
  const u16* gA = xb + (size_t)(mblk * 128 + row0) * D + kc;
  const u16* gB = W  + (size_t)(nblk * 128 + row0) * D + kc;

  for (int k0 = 0; k0 < D; k0 += 32) {
    bf16x8 va0 = *(const bf16x8*)(gA + k0);
    bf16x8 va1 = *(const bf16x8*)(gA + (size_t)64 * D + k0);
    bf16x8 vb0 = *(const bf16x8*)(gB + k0);
    bf16x8 vb1 = *(const bf16x8*)(gB + (size_t)64 * D + k0);
    __syncthreads();
    *(bf16x8*)(As + row0 * 40 + kc)        = va0;
    *(bf16x8*)(As + (row0 + 64) * 40 + kc) = va1;
    *(bf16x8*)(Bs + row0 * 40 + kc)        = vb0;
    *(bf16x8*)(Bs + (row0 + 64) * 40 + kc) = vb1;
    __syncthreads();
    bf16x8 af[4], bfr[4];
    #pragma unroll
    for (int mt = 0; mt < 4; mt++) af[mt]  = *(const bf16x8*)(As + (wr * 64 + mt * 16 + l16) * 40 + quad * 8);
    #pragma unroll
    for (int nt = 0; nt < 4; nt++) bfr[nt] = *(const bf16x8*)(Bs + (wc * 64 + nt * 16 + l16) * 40 + quad * 8);
    #pragma unroll
    for (int mt = 0; mt < 4; mt++)
      #pragma unroll
      for (int nt = 0; nt < 4; nt++)
        acc[mt][nt] = MFMA(af[mt], bfr[nt], acc[mt][nt]);
  }

  const float qscale = 0.18033688011112042f;  // 0.125 * log2(e)
  #pragma unroll
  for (int mt = 0; mt < 4; mt++) {
    int m0 = mblk * 128 + wr * 64 + mt * 16 + quad * 4;
    #pragma unroll
    for (int nt = 0; nt < 4; nt++) {
      int n = nblk * 128 + wc * 64 + nt * 16 + l16;
      int h = n >> 6, hd = n & 63;
      if (z == 2) {
        int b = m0 >> 12, s0 = m0 & 4095;
        u16* p = Vt + (((size_t)(b * H + h) * HD + hd)) * S + s0;
        uint2 pk;
        pk.x = (unsigned)f2b(acc[mt][nt][0]) | ((unsigned)f2b(acc[mt][nt][1]) << 16);
        pk.y = (unsigned)f2b(acc[mt][nt][2]) | ((unsigned)f2b(acc[mt][nt][3]) << 16);
        *(uint2*)p = pk;
      } else {
        u16* dst = (z == 0) ? Qb : Kb;
        float sc = (z == 0) ? qscale : 1.0f;
        #pragma unroll
        for (int r = 0; r < 4; r++) {
          int m = m0 + r; int b = m >> 12, s = m & 4095;
          dst[((size_t)(b * H + h) * S + s) * HD + hd] = f2b(acc[mt][nt][r] * sc);
        }
      }
    }
  }
}

// ---------------- flash attention (transposed: S^T = K Q^T, O^T = V^T P^T) ----------------
// grid (24, 32): x = bh (XCD = bh%8 locality), y = pr; block handles qtiles {pr, 63-pr} (64 queries each).
// 4 waves, each owns 16 query rows independently. kv tiles of 128 keys; diagonal via mask only.
__global__ __launch_bounds__(256, 3) void attn(
    const u16* __restrict__ Qb, const u16* __restrict__ Kb,
    const u16* __restrict__ Vt, u16* __restrict__ ctx)
{
  __shared__ __align__(16) u16 Pb[4][16 * 136];  // per-wave P: row=query(16), col=key(128), stride 136
  const int t = threadIdx.x, w = t >> 6, lane = t & 63, quad = lane >> 4, l16 = lane & 15;
  const int bh = blockIdx.x, pr = blockIdx.y;
  const u16* Qh = Qb + (size_t)bh * S * HD;
  const u16* Kh = Kb + (size_t)bh * S * HD;
  const u16* Vh = Vt + (size_t)bh * S * HD;   // [64][4096]
  u16* Pw = &Pb[w][0];
  const int b = bh / H, h = bh % H;

  for (int half = 0; half < 2; half++) {
    const int qtile = (half == 0) ? pr : (63 - pr);
    const int q0 = qtile * 64;
    const int qr = q0 + w * 16 + l16;          // this lane's query row

    // Q fragments (B-operand layout): lane holds Q[qr][ks*32+quad*8 ..+7]
    bf16x8 qf[2];
    #pragma unroll
    for (int ks = 0; ks < 2; ks++)
      qf[ks] = *(const bf16x8*)(Qh + (size_t)qr * HD + ks * 32 + quad * 8);

    f32x4 ao[4];                // O^T acc: row=hd (co*16+quad*4+r), col=query (l16)
    #pragma unroll
    for (int co = 0; co < 4; co++) ao[co] = (f32x4){0.f, 0.f, 0.f, 0.f};
    float mrun = -1e30f, lrun = 0.f;

    for (int kv0 = 0; kv0 <= q0; kv0 += 128) {
      const bool diag = (kv0 + 128 > q0);      // block-uniform
      f32x4 sacc[8];
      #pragma unroll
      for (int ct = 0; ct < 8; ct++) sacc[ct] = (f32x4){0.f, 0.f, 0.f, 0.f};

      // S^T = K Q^T : row=key (ct*16+quad*4+r), col=query (l16)
      #pragma unroll
      for (int ct = 0; ct < 8; ct++) {
        bf16x8 kf0 = *(const bf16x8*)(Kh + (size_t)(kv0 + ct * 16 + l16) * HD +  0 + quad * 8);
        bf16x8 kf1 = *(const bf16x8*)(Kh + (size_t)(kv0 + ct * 16 + l16) * HD + 32 + quad * 8);
        sacc[ct] = MFMA(kf0, qf[0], sacc[ct]);
        sacc[ct] = MFMA(kf1, qf[1], sacc[ct]);
      }

      if (diag) {
        #pragma unroll
        for (int ct = 0; ct < 8; ct++)
          #pragma unroll
          for (int r = 0; r < 4; r++) {
            int key = kv0 + ct * 16 + quad * 4 + r;
            if (key > qr) sacc[ct][r] = -1e30f;
          }
      }

      // online softmax (scores already scaled by 0.125*log2e -> use exp2)
      float tm = -1e30f;
      #pragma unroll
      for (int ct = 0; ct < 8; ct++)
        #pragma unroll
        for (int r = 0; r < 4; r++) tm = fmaxf(tm, sacc[ct][r]);
      tm = fmaxf(tm, __shfl_xor(tm, 16, 64));
      tm = fmaxf(tm, __shfl_xor(tm, 32, 64));
      float mnew = fmaxf(mrun, tm);
      float alpha = __builtin_amdgcn_exp2f(mrun - mnew);
      mrun = mnew;

      float ts = 0.f;
      #pragma unroll
      for (int ct = 0; ct < 8; ct++) {
        float p0 = __builtin_amdgcn_exp2f(sacc[ct][0] - mnew);
        float p1 = __builtin_amdgcn_exp2f(sacc[ct][1] - mnew);
        float p2 = __builtin_amdgcn_exp2f(sacc[ct][2] - mnew);
        float p3 = __builtin_amdgcn_exp2f(sacc[ct][3] - mnew);
        ts += (p0 + p1) + (p2 + p3);
        uint2 pk;
        pk.x = pack_bf16_trunc(p0, p1);
        pk.y = pack_bf16_trunc(p2, p3);
        *(uint2*)(Pw + l16 * 136 + ct * 16 + quad * 4) = pk;  // 4 consecutive keys
      }
      ts += __shfl_xor(ts, 16, 64);
      ts += __shfl_xor(ts, 32, 64);
      lrun = lrun * alpha + ts;
      #pragma unroll
      for (int co = 0; co < 4; co++)
        #pragma unroll
        for (int r = 0; r < 4; r++) ao[co][r] *= alpha;

      // O^T += V^T P^T  (A = V^T from Vt; B = P^T from per-wave LDS — no barrier)
      #pragma unroll
      for (int ks = 0; ks < 4; ks++) {
        bf16x8 pf = *(const bf16x8*)(Pw + l16 * 136 + ks * 32 + quad * 8);
        #pragma unroll
        for (int co = 0; co < 4; co++) {
          bf16x8 vf = *(const bf16x8*)(Vh + (size_t)(co * 16 + l16) * S + kv0 + ks * 32 + quad * 8);
          ao[co] = MFMA(vf, pf, ao[co]);
        }
      }
    }

    // epilogue: lane holds hd = co*16+quad*4+{0..3} for query l16 -> packed 8B store
    float inv = 1.0f / lrun;
    int token = b * S + qr;
    #pragma unroll
    for (int co = 0; co < 4; co++) {
      uint2 pk;
      pk.x = (unsigned)f2b(ao[co][0] * inv) | ((unsigned)f2b(ao[co][1] * inv) << 16);
      pk.y = (unsigned)f2b(ao[co][2] * inv) | ((unsigned)f2b(ao[co][3] * inv) << 16);
      *(uint2*)(ctx + (size_t)token * D + h * HD + co * 16 + quad * 4) = pk;
    }
  }
}

// ---------------- output projection: ctx[8192,768] x Wo^T + bias -> fp32 out
__global__ __launch_bounds__(256, 2) void out_gemm(
    const u16* __restrict__ ctx, const u16* __restrict__ wo,
    const float* __restrict__ bias, float* __restrict__ out)
{
  __shared__ __align__(16) u16 As[128 * 40];
  __shared__ __align__(16) u16 Bs[128 * 40];
  const int t = threadIdx.x;
  const int mblk = blockIdx.x, nblk = blockIdx.y;
  const int w = t >> 6, lane = t & 63, quad = lane >> 4, l16 = lane & 15;
  const int wr = w >> 1, wc = w & 1;

  f32x4 acc[4][4];
  #pragma unroll
  for (int i = 0; i < 4; i++)
    #pragma unroll
    for (int j = 0; j < 4; j++) acc[i][j] = (f32x4){0.f, 0.f, 0.f, 0.f};

  const int row0 = t >> 2;
  const int kc   = (t & 3) * 8;
  const u16* gA = ctx + (size_t)(mblk * 128 + row0) * D + kc;
  const u16* gB = wo  + (size_t)(nblk * 128 + row0) * D + kc;

  for (int k0 = 0; k0 < D; k0 += 32) {
    bf16x8 va0 = *(const bf16x8*)(gA + k0);
    bf16x8 va1 = *(const bf16x8*)(gA + (size_t)64 * D + k0);
    bf16x8 vb0 = *(const bf16x8*)(gB + k0);
    bf16x8 vb1 = *(const bf16x8*)(gB + (size_t)64 * D + k0);
    __syncthreads();
    *(bf16x8*)(As + row0 * 40 + kc)        = va0;
    *(bf16x8*)(As + (row0 + 64) * 40 + kc) = va1;
    *(bf16x8*)(Bs + row0 * 40 + kc)        = vb0;
    *(bf16x8*)(Bs + (row0 + 64) * 40 + kc) = vb1;
    __syncthreads();
    bf16x8 af[4], bfr[4];
    #pragma unroll
    for (int mt = 0; mt < 4; mt++) af[mt]  = *(const bf16x8*)(As + (wr * 64 + mt * 16 + l16) * 40 + quad * 8);
    #pragma unroll
    for (int nt = 0; nt < 4; nt++) bfr[nt] = *(const bf16x8*)(Bs + (wc * 64 + nt * 16 + l16) * 40 + quad * 8);
    #pragma unroll
    for (int mt = 0; mt < 4; mt++)
      #pragma unroll
      for (int nt = 0; nt < 4; nt++)
        acc[mt][nt] = MFMA(af[mt], bfr[nt], acc[mt][nt]);
  }

  #pragma unroll
  for (int mt = 0; mt < 4; mt++) {
    int m0 = mblk * 128 + wr * 64 + mt * 16 + quad * 4;
    #pragma unroll
    for (int nt = 0; nt < 4; nt++) {
      int n = nblk * 128 + wc * 64 + nt * 16 + l16;
      float bv = bias[n];
      #pragma unroll
      for (int r = 0; r < 4; r++)
        out[(size_t)(m0 + r) * D + n] = acc[mt][nt][r] + bv;
    }
  }
}

// ---------------- host launch ----------------
extern "C" void kernel_launch(void* const* d_in, const int* in_sizes, int n_in,
                              void* d_out, int out_size, void* d_ws, size_t ws_size,
                              hipStream_t stream) {
  const float* x    = (const float*)d_in[0];
  const float* wq   = (const float*)d_in[1];
  const float* wk   = (const float*)d_in[2];
  const float* wv   = (const float*)d_in[3];
  const float* wo   = (const float*)d_in[4];
  const float* bo   = (const float*)d_in[5];
  float* out = (float*)d_out;

  u16* ws = (u16*)d_ws;
  const size_t NX = (size_t)2 * S * D;      // 6291456
  const size_t NW = (size_t)D * D;          // 589824
  u16* xb  = ws;                // [8192][768]; reused as ctx after qkv_gemm consumes it
  u16* wqb = ws + NX;
  u16* wkb = wqb + NW;
  u16* wvb = wkb + NW;
  u16* wob = wvb + NW;
  u16* Qb  = wob + NW;          // [2][12][4096][64]  (pre-scaled by 0.125*log2e)
  u16* Kb  = Qb + NX;
  u16* Vt  = Kb + NX;           // [2][12][64][4096]
  u16* ctx = xb;

  castk<<<(int)((NX / 4 + 255) / 256), 256, 0, stream>>>(x,  xb,  (int)(NX / 4));
  castk<<<(int)((NW / 4 + 255) / 256), 256, 0, stream>>>(wq, wqb, (int)(NW / 4));
  castk<<<(int)((NW / 4 + 255) / 256), 256, 0, stream>>>(wk, wkb, (int)(NW / 4));
  castk<<<(int)((NW / 4 + 255) / 256), 256, 0, stream>>>(wv, wvb, (int)(NW / 4));
  castk<<<(int)((NW / 4 + 255) / 256), 256, 0, stream>>>(wo, wob, (int)(NW / 4));

  qkv_gemm<<<dim3(64, 6, 3), 256, 0, stream>>>(xb, wqb, wkb, wvb, Qb, Kb, Vt);
  attn<<<dim3(2 * H, 32), 256, 0, stream>>>(Qb, Kb, Vt, ctx);
  out_gemm<<<dim3(64, 6), 256, 0, stream>>>(ctx, wob, bo, out);
}

// Round 4
// 365.286 us; speedup vs baseline: 1.3959x; 1.3959x over previous
//
#include <hip/hip_runtime.h>
#include <stdint.h>

typedef unsigned short u16;
typedef __attribute__((ext_vector_type(8))) short bf16x8;
typedef __attribute__((ext_vector_type(4))) float f32x4;

#define MFMA(a,b,c) __builtin_amdgcn_mfma_f32_16x16x32_bf16((a),(b),(c),0,0,0)

static constexpr int S  = 4096;
static constexpr int D  = 768;
static constexpr int H  = 12;
static constexpr int HD = 64;

// float -> bf16 round-nearest-even
__device__ __forceinline__ u16 f2b(float f){
  union { float f; unsigned u; } v; v.f = f;
  unsigned r = (v.u + 0x7fffu + ((v.u >> 16) & 1u)) >> 16;
  return (u16)r;
}

// pack 2 floats -> 2 bf16 (truncation) in ONE v_perm_b32
__device__ __forceinline__ unsigned pack_bf16_trunc(float a, float b){
  return __builtin_amdgcn_perm(__float_as_uint(b), __float_as_uint(a), 0x07060302u);
}

// ---------------- cast fp32 -> bf16, 4 elems/thread ----------------
__global__ void castk(const float* __restrict__ s, u16* __restrict__ d, int n4){
  int i = blockIdx.x * 256 + threadIdx.x;
  if (i >= n4) return;
  float4 v = ((const float4*)s)[i];
  uint2 o;
  o.x = (unsigned)f2b(v.x) | ((unsigned)f2b(v.y) << 16);
  o.y = (unsigned)f2b(v.z) | ((unsigned)f2b(v.w) << 16);
  ((uint2*)d)[i] = o;
}

// ---------------- QKV GEMM: [8192,768] x Wt[768,768] -> Q/K ([b][h][s][hd]) or Vt ([b][h][hd][s])
// Q is pre-scaled by 0.125*log2(e) so attention softmax can use raw exp2.
__global__ __launch_bounds__(256, 2) void qkv_gemm(
    const u16* __restrict__ xb, const u16* __restrict__ wq, const u16* __restrict__ wk,
    const u16* __restrict__ wv, u16* __restrict__ Qb, u16* __restrict__ Kb, u16* __restrict__ Vt)
{
  __shared__ __align__(16) u16 As[128 * 40];
  __shared__ __align__(16) u16 Bs[128 * 40];
  const int t = threadIdx.x;
  const int mblk = blockIdx.x, nblk = blockIdx.y, z = blockIdx.z;
  const u16* W = (z == 0) ? wq : (z == 1) ? wk : wv;
  const int w = t >> 6, lane = t & 63, quad = lane >> 4, l16 = lane & 15;
  const int wr = w >> 1, wc = w & 1;

  f32x4 acc[4][4];
  #pragma unroll
  for (int i = 0; i < 4; i++)
    #pragma unroll
    for (int j = 0; j < 4; j++) acc[i][j] = (f32x4){0.f, 0.f, 0.f, 0.f};

  const int row0 = t >> 2;
  const int kc   = (t & 3) * 8;
  const u16* gA = xb + (size_t)(mblk * 128 + row0) * D + kc;
  const u16* gB = W  + (size_t)(nblk * 128 + row0) * D + kc;

  for (int k0 = 0; k0 < D; k0 += 32) {
    bf16x8 va0 = *(const bf16x8*)(gA + k0);
    bf16x8 va1 = *(const bf16x8*)(gA + (size_t)64 * D + k0);
    bf16x8 vb0 = *(const bf16x8*)(gB + k0);
    bf16x8 vb1 = *(const bf16x8*)(gB + (size_t)64 * D + k0);
    __syncthreads();
    *(bf16x8*)(As + row0 * 40 + kc)        = va0;
    *(bf16x8*)(As + (row0 + 64) * 40 + kc) = va1;
    *(bf16x8*)(Bs + row0 * 40 + kc)        = vb0;
    *(bf16x8*)(Bs + (row0 + 64) * 40 + kc) = vb1;
    __syncthreads();
    bf16x8 af[4], bfr[4];
    #pragma unroll
    for (int mt = 0; mt < 4; mt++) af[mt]  = *(const bf16x8*)(As + (wr * 64 + mt * 16 + l16) * 40 + quad * 8);
    #pragma unroll
    for (int nt = 0; nt < 4; nt++) bfr[nt] = *(const bf16x8*)(Bs + (wc * 64 + nt * 16 + l16) * 40 + quad * 8);
    #pragma unroll
    for (int mt = 0; mt < 4; mt++)
      #pragma unroll
      for (int nt = 0; nt < 4; nt++)
        acc[mt][nt] = MFMA(af[mt], bfr[nt], acc[mt][nt]);
  }

  const float qscale = 0.18033688011112042f;  // 0.125 * log2(e)
  #pragma unroll
  for (int mt = 0; mt < 4; mt++) {
    int m0 = mblk * 128 + wr * 64 + mt * 16 + quad * 4;
    #pragma unroll
    for (int nt = 0; nt < 4; nt++) {
      int n = nblk * 128 + wc * 64 + nt * 16 + l16;
      int h = n >> 6, hd = n & 63;
      if (z == 2) {
        int b = m0 >> 12, s0 = m0 & 4095;
        u16* p = Vt + (((size_t)(b * H + h) * HD + hd)) * S + s0;
        uint2 pk;
        pk.x = (unsigned)f2b(acc[mt][nt][0]) | ((unsigned)f2b(acc[mt][nt][1]) << 16);
        pk.y = (unsigned)f2b(acc[mt][nt][2]) | ((unsigned)f2b(acc[mt][nt][3]) << 16);
        *(uint2*)p = pk;
      } else {
        u16* dst = (z == 0) ? Qb : Kb;
        float sc = (z == 0) ? qscale : 1.0f;
        #pragma unroll
        for (int r = 0; r < 4; r++) {
          int m = m0 + r; int b = m >> 12, s = m & 4095;
          dst[((size_t)(b * H + h) * S + s) * HD + hd] = f2b(acc[mt][nt][r] * sc);
        }
      }
    }
  }
}

// ---------------- flash attention (transposed: S^T = K Q^T, O^T = V^T P^T) ----------------
// Workgroup = ONE wave (64 threads) owning 32 query rows (qt = 32-query tile).
// grid (24, 128): x = bh (XCD = bh%8 locality, 24%8==0), y -> qt = 127-y (longest blocks first).
// 3072 blocks all co-resident (12 waves/CU = 3/SIMD). kv tiles of 128 keys; wave-uniform
// ct_end/ks_end trims the partial diagonal tile; element mask for the last 32 keys.
__global__ __launch_bounds__(64, 3) void attn(
    const u16* __restrict__ Qb, const u16* __restrict__ Kb,
    const u16* __restrict__ Vt, u16* __restrict__ ctx)
{
  __shared__ __align__(16) u16 Pw[32 * 136];  // P: row=query(32), col=key(128), stride 136
  const int lane = threadIdx.x, quad = lane >> 4, l16 = lane & 15;
  const int bh = blockIdx.x;
  const int qt = 127 - blockIdx.y;           // descending task length
  const int q0 = qt * 32;
  const u16* Qh = Qb + (size_t)bh * S * HD;
  const u16* Kh = Kb + (size_t)bh * S * HD;
  const u16* Vh = Vt + (size_t)bh * S * HD;  // [64][4096]
  const int b = bh / H, h = bh % H;

  // Q fragments (B-operand layout): lane holds Q[q0+rt*16+l16][ks*32+quad*8 ..+7]
  bf16x8 qf[2][2];
  #pragma unroll
  for (int rt = 0; rt < 2; rt++)
    #pragma unroll
    for (int ks = 0; ks < 2; ks++)
      qf[rt][ks] = *(const bf16x8*)(Qh + (size_t)(q0 + rt * 16 + l16) * HD + ks * 32 + quad * 8);

  f32x4 ao[2][4];                 // O^T acc: row=hd (co*16+quad*4+r), col=query (rt*16+l16)
  #pragma unroll
  for (int rt = 0; rt < 2; rt++)
    #pragma unroll
    for (int co = 0; co < 4; co++) ao[rt][co] = (f32x4){0.f, 0.f, 0.f, 0.f};
  float mrun[2] = {-1e30f, -1e30f};
  float lrun[2] = {0.f, 0.f};

  const int kv_last = (q0 >> 7) << 7;          // last 128-key tile start
  for (int kv0 = 0; kv0 <= kv_last; kv0 += 128) {
    const bool diag = (kv0 == kv_last);
    const int ct_end = diag ? (((q0 & 127) + 32) >> 4) : 8;   // wave-uniform, even (2,4,6,8)
    f32x4 sacc[2][8];
    #pragma unroll
    for (int rt = 0; rt < 2; rt++)
      #pragma unroll
      for (int ct = 0; ct < 8; ct++) sacc[rt][ct] = (f32x4){0.f, 0.f, 0.f, 0.f};

    // S^T = K Q^T : row=key (ct*16+quad*4+r), col=query (l16)
    #pragma unroll
    for (int ct = 0; ct < 8; ct++) {
      if (ct < ct_end) {
        bf16x8 kf0 = *(const bf16x8*)(Kh + (size_t)(kv0 + ct * 16 + l16) * HD +  0 + quad * 8);
        bf16x8 kf1 = *(const bf16x8*)(Kh + (size_t)(kv0 + ct * 16 + l16) * HD + 32 + quad * 8);
        #pragma unroll
        for (int rt = 0; rt < 2; rt++) {
          sacc[rt][ct] = MFMA(kf0, qf[rt][0], sacc[rt][ct]);
          sacc[rt][ct] = MFMA(kf1, qf[rt][1], sacc[rt][ct]);
        }
      }
    }

    if (diag) {   // mask keys beyond each query row (only last tile can violate)
      #pragma unroll
      for (int rt = 0; rt < 2; rt++) {
        int qr = q0 + rt * 16 + l16;
        #pragma unroll
        for (int ct = 0; ct < 8; ct++) {
          if (ct < ct_end) {
            #pragma unroll
            for (int r = 0; r < 4; r++) {
              int key = kv0 + ct * 16 + quad * 4 + r;
              if (key > qr) sacc[rt][ct][r] = -1e30f;
            }
          }
        }
      }
    }

    // online softmax (scores pre-scaled by 0.125*log2e -> raw exp2)
    #pragma unroll
    for (int rt = 0; rt < 2; rt++) {
      float tm = -1e30f;
      #pragma unroll
      for (int ct = 0; ct < 8; ct++)
        if (ct < ct_end)
          #pragma unroll
          for (int r = 0; r < 4; r++) tm = fmaxf(tm, sacc[rt][ct][r]);
      tm = fmaxf(tm, __shfl_xor(tm, 16, 64));
      tm = fmaxf(tm, __shfl_xor(tm, 32, 64));
      float mnew = fmaxf(mrun[rt], tm);
      float alpha = __builtin_amdgcn_exp2f(mrun[rt] - mnew);
      mrun[rt] = mnew;

      float ts = 0.f;
      #pragma unroll
      for (int ct = 0; ct < 8; ct++) {
        if (ct < ct_end) {
          float p0 = __builtin_amdgcn_exp2f(sacc[rt][ct][0] - mnew);
          float p1 = __builtin_amdgcn_exp2f(sacc[rt][ct][1] - mnew);
          float p2 = __builtin_amdgcn_exp2f(sacc[rt][ct][2] - mnew);
          float p3 = __builtin_amdgcn_exp2f(sacc[rt][ct][3] - mnew);
          ts += (p0 + p1) + (p2 + p3);
          uint2 pk;
          pk.x = pack_bf16_trunc(p0, p1);
          pk.y = pack_bf16_trunc(p2, p3);
          *(uint2*)(Pw + (rt * 16 + l16) * 136 + ct * 16 + quad * 4) = pk;  // 4 consecutive keys
        }
      }
      ts += __shfl_xor(ts, 16, 64);
      ts += __shfl_xor(ts, 32, 64);
      lrun[rt] = lrun[rt] * alpha + ts;
      #pragma unroll
      for (int co = 0; co < 4; co++)
        #pragma unroll
        for (int r = 0; r < 4; r++) ao[rt][co][r] *= alpha;
    }

    // O^T += V^T P^T  (A = V^T from Vt; B = P^T from LDS — single wave, no barrier)
    const int ks_end = (diag ? (((q0 & 127) + 32) >> 5) : 4);  // ct_end/2
    #pragma unroll
    for (int ks = 0; ks < 4; ks++) {
      if (ks < ks_end) {
        bf16x8 pf0 = *(const bf16x8*)(Pw + (0  + l16) * 136 + ks * 32 + quad * 8);
        bf16x8 pf1 = *(const bf16x8*)(Pw + (16 + l16) * 136 + ks * 32 + quad * 8);
        #pragma unroll
        for (int co = 0; co < 4; co++) {
          bf16x8 vf = *(const bf16x8*)(Vh + (size_t)(co * 16 + l16) * S + kv0 + ks * 32 + quad * 8);
          ao[0][co] = MFMA(vf, pf0, ao[0][co]);
          ao[1][co] = MFMA(vf, pf1, ao[1][co]);
        }
      }
    }
  }

  // epilogue: lane holds hd = co*16+quad*4+{0..3} for query rt*16+l16 -> packed 8B store
  #pragma unroll
  for (int rt = 0; rt < 2; rt++) {
    float inv = 1.0f / lrun[rt];
    int token = b * S + q0 + rt * 16 + l16;
    #pragma unroll
    for (int co = 0; co < 4; co++) {
      uint2 pk;
      pk.x = (unsigned)f2b(ao[rt][co][0] * inv) | ((unsigned)f2b(ao[rt][co][1] * inv) << 16);
      pk.y = (unsigned)f2b(ao[rt][co][2] * inv) | ((unsigned)f2b(ao[rt][co][3] * inv) << 16);
      *(uint2*)(ctx + (size_t)token * D + h * HD + co * 16 + quad * 4) = pk;
    }
  }
}

// ---------------- output projection: ctx[8192,768] x Wo^T + bias -> fp32 out
__global__ __launch_bounds__(256, 2) void out_gemm(
    const u16* __restrict__ ctx, const u16* __restrict__ wo,
    const float* __restrict__ bias, float* __restrict__ out)
{
  __shared__ __align__(16) u16 As[128 * 40];
  __shared__ __align__(16) u16 Bs[128 * 40];
  const int t = threadIdx.x;
  const int mblk = blockIdx.x, nblk = blockIdx.y;
  const int w = t >> 6, lane = t & 63, quad = lane >> 4, l16 = lane & 15;
  const int wr = w >> 1, wc = w & 1;

  f32x4 acc[4][4];
  #pragma unroll
  for (int i = 0; i < 4; i++)
    #pragma unroll
    for (int j = 0; j < 4; j++) acc[i][j] = (f32x4){0.f, 0.f, 0.f, 0.f};

  const int row0 = t >> 2;
  const int kc   = (t & 3) * 8;
  const u16* gA = ctx + (size_t)(mblk * 128 + row0) * D + kc;
  const u16* gB = wo  + (size_t)(nblk * 128 + row0) * D + kc;

  for (int k0 = 0; k0 < D; k0 += 32) {
    bf16x8 va0 = *(const bf16x8*)(gA + k0);
    bf16x8 va1 = *(const bf16x8*)(gA + (size_t)64 * D + k0);
    bf16x8 vb0 = *(const bf16x8*)(gB + k0);
    bf16x8 vb1 = *(const bf16x8*)(gB + (size_t)64 * D + k0);
    __syncthreads();
    *(bf16x8*)(As + row0 * 40 + kc)        = va0;
    *(bf16x8*)(As + (row0 + 64) * 40 + kc) = va1;
    *(bf16x8*)(Bs + row0 * 40 + kc)        = vb0;
    *(bf16x8*)(Bs + (row0 + 64) * 40 + kc) = vb1;
    __syncthreads();
    bf16x8 af[4], bfr[4];
    #pragma unroll
    for (int mt = 0; mt < 4; mt++) af[mt]  = *(const bf16x8*)(As + (wr * 64 + mt * 16 + l16) * 40 + quad * 8);
    #pragma unroll
    for (int nt = 0; nt < 4; nt++) bfr[nt] = *(const bf16x8*)(Bs + (wc * 64 + nt * 16 + l16) * 40 + quad * 8);
    #pragma unroll
    for (int mt = 0; mt < 4; mt++)
      #pragma unroll
      for (int nt = 0; nt < 4; nt++)
        acc[mt][nt] = MFMA(af[mt], bfr[nt], acc[mt][nt]);
  }

  #pragma unroll
  for (int mt = 0; mt < 4; mt++) {
    int m0 = mblk * 128 + wr * 64 + mt * 16 + quad * 4;
    #pragma unroll
    for (int nt = 0; nt < 4; nt++) {
      int n = nblk * 128 + wc * 64 + nt * 16 + l16;
      float bv = bias[n];
      #pragma unroll
      for (int r = 0; r < 4; r++)
        out[(size_t)(m0 + r) * D + n] = acc[mt][nt][r] + bv;
    }
  }
}

// ---------------- host launch ----------------
extern "C" void kernel_launch(void* const* d_in, const int* in_sizes, int n_in,
                              void* d_out, int out_size, void* d_ws, size_t ws_size,
                              hipStream_t stream) {
  const float* x    = (const float*)d_in[0];
  const float* wq   = (const float*)d_in[1];
  const float* wk   = (const float*)d_in[2];
  const float* wv   = (const float*)d_in[3];
  const float* wo   = (const float*)d_in[4];
  const float* bo   = (const float*)d_in[5];
  float* out = (float*)d_out;

  u16* ws = (u16*)d_ws;
  const size_t NX = (size_t)2 * S * D;      // 6291456
  const size_t NW = (size_t)D * D;          // 589824
  u16* xb  = ws;                // [8192][768]; reused as ctx after qkv_gemm consumes it
  u16* wqb = ws + NX;
  u16* wkb = wqb + NW;
  u16* wvb = wkb + NW;
  u16* wob = wvb + NW;
  u16* Qb  = wob + NW;          // [2][12][4096][64]  (pre-scaled by 0.125*log2e)
  u16* Kb  = Qb + NX;
  u16* Vt  = Kb + NX;           // [2][12][64][4096]
  u16* ctx = xb;

  castk<<<(int)((NX / 4 + 255) / 256), 256, 0, stream>>>(x,  xb,  (int)(NX / 4));
  castk<<<(int)((NW / 4 + 255) / 256), 256, 0, stream>>>(wq, wqb, (int)(NW / 4));
  castk<<<(int)((NW / 4 + 255) / 256), 256, 0, stream>>>(wk, wkb, (int)(NW / 4));
  castk<<<(int)((NW / 4 + 255) / 256), 256, 0, stream>>>(wv, wvb, (int)(NW / 4));
  castk<<<(int)((NW / 4 + 255) / 256), 256, 0, stream>>>(wo, wob, (int)(NW / 4));

  qkv_gemm<<<dim3(64, 6, 3), 256, 0, stream>>>(xb, wqb, wkb, wvb, Qb, Kb, Vt);
  attn<<<dim3(24, 128), 64, 0, stream>>>(Qb, Kb, Vt, ctx);
  out_gemm<<<dim3(64, 6), 256, 0, stream>>>(ctx, wob, bo, out);
}

// Round 5
// 262.097 us; speedup vs baseline: 1.9455x; 1.3937x over previous
//
#include <hip/hip_runtime.h>
#include <stdint.h>

typedef unsigned short u16;
typedef __attribute__((ext_vector_type(8))) short bf16x8;
typedef __attribute__((ext_vector_type(4))) float f32x4;

#define MFMA(a,b,c) __builtin_amdgcn_mfma_f32_16x16x32_bf16((a),(b),(c),0,0,0)

static constexpr int S  = 4096;
static constexpr int D  = 768;
static constexpr int H  = 12;
static constexpr int HD = 64;

// float -> bf16 round-nearest-even
__device__ __forceinline__ u16 f2b(float f){
  union { float f; unsigned u; } v; v.f = f;
  unsigned r = (v.u + 0x7fffu + ((v.u >> 16) & 1u)) >> 16;
  return (u16)r;
}

// pack 2 floats -> 2 bf16 (truncation) in ONE v_perm_b32
__device__ __forceinline__ unsigned pack_bf16_trunc(float a, float b){
  return __builtin_amdgcn_perm(__float_as_uint(b), __float_as_uint(a), 0x07060302u);
}

// ---------------- cast fp32 -> bf16, 4 elems/thread ----------------
__global__ void castk(const float* __restrict__ s, u16* __restrict__ d, int n4){
  int i = blockIdx.x * 256 + threadIdx.x;
  if (i >= n4) return;
  float4 v = ((const float4*)s)[i];
  uint2 o;
  o.x = (unsigned)f2b(v.x) | ((unsigned)f2b(v.y) << 16);
  o.y = (unsigned)f2b(v.z) | ((unsigned)f2b(v.w) << 16);
  ((uint2*)d)[i] = o;
}

// ---------------- QKV GEMM: [8192,768] x Wt[768,768] -> Q/K ([b][h][s][hd]) or Vt ([b][h][hd][s])
// Q is pre-scaled by 0.125*log2(e) so attention softmax can use raw exp2.
__global__ __launch_bounds__(256, 2) void qkv_gemm(
    const u16* __restrict__ xb, const u16* __restrict__ wq, const u16* __restrict__ wk,
    const u16* __restrict__ wv, u16* __restrict__ Qb, u16* __restrict__ Kb, u16* __restrict__ Vt)
{
  __shared__ __align__(16) u16 As[128 * 40];
  __shared__ __align__(16) u16 Bs[128 * 40];
  const int t = threadIdx.x;
  const int mblk = blockIdx.x, nblk = blockIdx.y, z = blockIdx.z;
  const u16* W = (z == 0) ? wq : (z == 1) ? wk : wv;
  const int w = t >> 6, lane = t & 63, quad = lane >> 4, l16 = lane & 15;
  const int wr = w >> 1, wc = w & 1;

  f32x4 acc[4][4];
  #pragma unroll
  for (int i = 0; i < 4; i++)
    #pragma unroll
    for (int j = 0; j < 4; j++) acc[i][j] = (f32x4){0.f, 0.f, 0.f, 0.f};

  const int row0 = t >> 2;
  const int kc   = (t & 3) * 8;
  const u16* gA = xb + (size_t)(mblk * 128 + row0) * D + kc;
  const u16* gB = W  + (size_t)(nblk * 128 + row0) * D + kc;

  for (int k0 = 0; k0 < D; k0 += 32) {
    bf16x8 va0 = *(const bf16x8*)(gA + k0);
    bf16x8 va1 = *(const bf16x8*)(gA + (size_t)64 * D + k0);
    bf16x8 vb0 = *(const bf16x8*)(gB + k0);
    bf16x8 vb1 = *(const bf16x8*)(gB + (size_t)64 * D + k0);
    __syncthreads();
    *(bf16x8*)(As + row0 * 40 + kc)        = va0;
    *(bf16x8*)(As + (row0 + 64) * 40 + kc) = va1;
    *(bf16x8*)(Bs + row0 * 40 + kc)        = vb0;
    *(bf16x8*)(Bs + (row0 + 64) * 40 + kc) = vb1;
    __syncthreads();
    bf16x8 af[4], bfr[4];
    #pragma unroll
    for (int mt = 0; mt < 4; mt++) af[mt]  = *(const bf16x8*)(As + (wr * 64 + mt * 16 + l16) * 40 + quad * 8);
    #pragma unroll
    for (int nt = 0; nt < 4; nt++) bfr[nt] = *(const bf16x8*)(Bs + (wc * 64 + nt * 16 + l16) * 40 + quad * 8);
    #pragma unroll
    for (int mt = 0; mt < 4; mt++)
      #pragma unroll
      for (int nt = 0; nt < 4; nt++)
        acc[mt][nt] = MFMA(af[mt], bfr[nt], acc[mt][nt]);
  }

  const float qscale = 0.18033688011112042f;  // 0.125 * log2(e)
  #pragma unroll
  for (int mt = 0; mt < 4; mt++) {
    int m0 = mblk * 128 + wr * 64 + mt * 16 + quad * 4;
    #pragma unroll
    for (int nt = 0; nt < 4; nt++) {
      int n = nblk * 128 + wc * 64 + nt * 16 + l16;
      int h = n >> 6, hd = n & 63;
      if (z == 2) {
        int b = m0 >> 12, s0 = m0 & 4095;
        u16* p = Vt + (((size_t)(b * H + h) * HD + hd)) * S + s0;
        uint2 pk;
        pk.x = (unsigned)f2b(acc[mt][nt][0]) | ((unsigned)f2b(acc[mt][nt][1]) << 16);
        pk.y = (unsigned)f2b(acc[mt][nt][2]) | ((unsigned)f2b(acc[mt][nt][3]) << 16);
        *(uint2*)p = pk;
      } else {
        u16* dst = (z == 0) ? Qb : Kb;
        float sc = (z == 0) ? qscale : 1.0f;
        #pragma unroll
        for (int r = 0; r < 4; r++) {
          int m = m0 + r; int b = m >> 12, s = m & 4095;
          dst[((size_t)(b * H + h) * S + s) * HD + hd] = f2b(acc[mt][nt][r] * sc);
        }
      }
    }
  }
}

// ---------------- flash attention (transposed: S^T = K Q^T, O^T = V^T P^T) ----------------
// Block = 4 waves × 32 queries = 128 queries; K/V tiles (128 keys) staged in LDS ONCE per
// kv-iter and shared by all 4 waves (4x cut in L2 traffic vs per-wave direct loads).
// grid (24, 32): x = bh (XCD = bh%8), y -> qtile = 31-y (longest blocks first).
__global__ __launch_bounds__(256, 2) void attn(
    const u16* __restrict__ Qb, const u16* __restrict__ Kb,
    const u16* __restrict__ Vt, u16* __restrict__ ctx)
{
  __shared__ __align__(16) u16 Ks[128 * 72];    // K tile  [key][hd],  stride 72
  __shared__ __align__(16) u16 Vts[64 * 136];   // V^T tile [hd][key], stride 136
  __shared__ __align__(16) u16 Pb[4][32 * 136]; // per-wave P: [query][key], stride 136
  const int t = threadIdx.x, w = t >> 6, lane = t & 63, quad = lane >> 4, l16 = lane & 15;
  const int bh = blockIdx.x;
  const int qtile = 31 - (int)blockIdx.y;       // descending task length
  const int q0 = qtile * 128;
  const u16* Qh = Qb + (size_t)bh * S * HD;
  const u16* Kh = Kb + (size_t)bh * S * HD;
  const u16* Vh = Vt + (size_t)bh * S * HD;     // [64][4096]
  u16* Pw = &Pb[w][0];
  const int b = bh / H, h = bh % H;

  // Q fragments (B-operand layout): lane holds Q[q0+w*32+rt*16+l16][ks*32+quad*8 ..+7]
  bf16x8 qf[2][2];
  #pragma unroll
  for (int rt = 0; rt < 2; rt++)
    #pragma unroll
    for (int ks = 0; ks < 2; ks++)
      qf[rt][ks] = *(const bf16x8*)(Qh + (size_t)(q0 + w * 32 + rt * 16 + l16) * HD + ks * 32 + quad * 8);

  f32x4 ao[2][4];                 // O^T acc: row=hd (co*16+quad*4+r), col=query (rt*16+l16)
  #pragma unroll
  for (int rt = 0; rt < 2; rt++)
    #pragma unroll
    for (int co = 0; co < 4; co++) ao[rt][co] = (f32x4){0.f, 0.f, 0.f, 0.f};
  float mrun[2] = {-1e30f, -1e30f};
  float lrun[2] = {0.f, 0.f};

  // staging addresses: K: thread t -> key row t>>1, hd (t&1)*32, 64B (4 x dwordx4)
  //                    V: thread t -> hd row t>>2, key (t&3)*32, 64B
  const u16* gK = Kh + (size_t)(t >> 1) * HD + (t & 1) * 32;
  u16*       sK = Ks + (t >> 1) * 72 + (t & 1) * 32;
  const u16* gV = Vh + (size_t)(t >> 2) * S + (t & 3) * 32;
  u16*       sV = Vts + (t >> 2) * 136 + (t & 3) * 32;

  for (int kv0 = 0; kv0 <= q0; kv0 += 128) {
    const bool diag = (kv0 == q0);
    const int ct_end = diag ? (2 * w + 2) : 8;   // wave-uniform
    const int ks_end = diag ? (w + 1) : 4;

    // ---- stage K & V tiles into LDS (shared by all 4 waves) ----
    {
      const u16* g0 = gK + (size_t)kv0 * HD;
      bf16x8 k0 = *(const bf16x8*)(g0 +  0);
      bf16x8 k1 = *(const bf16x8*)(g0 +  8);
      bf16x8 k2 = *(const bf16x8*)(g0 + 16);
      bf16x8 k3 = *(const bf16x8*)(g0 + 24);
      const u16* g1 = gV + kv0;
      bf16x8 v0 = *(const bf16x8*)(g1 +  0);
      bf16x8 v1 = *(const bf16x8*)(g1 +  8);
      bf16x8 v2 = *(const bf16x8*)(g1 + 16);
      bf16x8 v3 = *(const bf16x8*)(g1 + 24);
      __syncthreads();           // prior iter's LDS reads complete
      *(bf16x8*)(sK +  0) = k0;
      *(bf16x8*)(sK +  8) = k1;
      *(bf16x8*)(sK + 16) = k2;
      *(bf16x8*)(sK + 24) = k3;
      *(bf16x8*)(sV +  0) = v0;
      *(bf16x8*)(sV +  8) = v1;
      *(bf16x8*)(sV + 16) = v2;
      *(bf16x8*)(sV + 24) = v3;
      __syncthreads();
    }

    f32x4 sacc[2][8];
    #pragma unroll
    for (int rt = 0; rt < 2; rt++)
      #pragma unroll
      for (int ct = 0; ct < 8; ct++) sacc[rt][ct] = (f32x4){0.f, 0.f, 0.f, 0.f};

    // S^T = K Q^T : A = K frag from LDS (m=key), B = Q regs (n=query)
    #pragma unroll
    for (int ct = 0; ct < 8; ct++) {
      if (ct < ct_end) {
        bf16x8 kf0 = *(const bf16x8*)(Ks + (ct * 16 + l16) * 72 +  0 + quad * 8);
        bf16x8 kf1 = *(const bf16x8*)(Ks + (ct * 16 + l16) * 72 + 32 + quad * 8);
        #pragma unroll
        for (int rt = 0; rt < 2; rt++) {
          sacc[rt][ct] = MFMA(kf0, qf[rt][0], sacc[rt][ct]);
          sacc[rt][ct] = MFMA(kf1, qf[rt][1], sacc[rt][ct]);
        }
      }
    }

    if (diag) {   // mask keys beyond each query row
      #pragma unroll
      for (int rt = 0; rt < 2; rt++) {
        int qr = q0 + w * 32 + rt * 16 + l16;
        #pragma unroll
        for (int ct = 0; ct < 8; ct++) {
          if (ct < ct_end) {
            #pragma unroll
            for (int r = 0; r < 4; r++) {
              int key = kv0 + ct * 16 + quad * 4 + r;
              if (key > qr) sacc[rt][ct][r] = -1e30f;
            }
          }
        }
      }
    }

    // online softmax (scores pre-scaled by 0.125*log2e -> raw exp2)
    #pragma unroll
    for (int rt = 0; rt < 2; rt++) {
      float tm = -1e30f;
      #pragma unroll
      for (int ct = 0; ct < 8; ct++)
        if (ct < ct_end)
          #pragma unroll
          for (int r = 0; r < 4; r++) tm = fmaxf(tm, sacc[rt][ct][r]);
      tm = fmaxf(tm, __shfl_xor(tm, 16, 64));
      tm = fmaxf(tm, __shfl_xor(tm, 32, 64));
      float mnew = fmaxf(mrun[rt], tm);
      float alpha = __builtin_amdgcn_exp2f(mrun[rt] - mnew);
      mrun[rt] = mnew;

      float ts = 0.f;
      #pragma unroll
      for (int ct = 0; ct < 8; ct++) {
        if (ct < ct_end) {
          float p0 = __builtin_amdgcn_exp2f(sacc[rt][ct][0] - mnew);
          float p1 = __builtin_amdgcn_exp2f(sacc[rt][ct][1] - mnew);
          float p2 = __builtin_amdgcn_exp2f(sacc[rt][ct][2] - mnew);
          float p3 = __builtin_amdgcn_exp2f(sacc[rt][ct][3] - mnew);
          ts += (p0 + p1) + (p2 + p3);
          uint2 pk;
          pk.x = pack_bf16_trunc(p0, p1);
          pk.y = pack_bf16_trunc(p2, p3);
          *(uint2*)(Pw + (rt * 16 + l16) * 136 + ct * 16 + quad * 4) = pk;  // 4 consecutive keys
        }
      }
      ts += __shfl_xor(ts, 16, 64);
      ts += __shfl_xor(ts, 32, 64);
      lrun[rt] = lrun[rt] * alpha + ts;
      #pragma unroll
      for (int co = 0; co < 4; co++)
        #pragma unroll
        for (int r = 0; r < 4; r++) ao[rt][co][r] *= alpha;
    }

    // O^T += V^T P^T  (A = V^T frag from LDS; B = P^T frag from per-wave LDS)
    #pragma unroll
    for (int ks = 0; ks < 4; ks++) {
      if (ks < ks_end) {
        bf16x8 pf0 = *(const bf16x8*)(Pw + (0  + l16) * 136 + ks * 32 + quad * 8);
        bf16x8 pf1 = *(const bf16x8*)(Pw + (16 + l16) * 136 + ks * 32 + quad * 8);
        #pragma unroll
        for (int co = 0; co < 4; co++) {
          bf16x8 vf = *(const bf16x8*)(Vts + (co * 16 + l16) * 136 + ks * 32 + quad * 8);
          ao[0][co] = MFMA(vf, pf0, ao[0][co]);
          ao[1][co] = MFMA(vf, pf1, ao[1][co]);
        }
      }
    }
  }

  // epilogue: lane holds hd = co*16+quad*4+{0..3} for query rt*16+l16 -> packed 8B store
  #pragma unroll
  for (int rt = 0; rt < 2; rt++) {
    float inv = 1.0f / lrun[rt];
    int token = b * S + q0 + w * 32 + rt * 16 + l16;
    #pragma unroll
    for (int co = 0; co < 4; co++) {
      uint2 pk;
      pk.x = (unsigned)f2b(ao[rt][co][0] * inv) | ((unsigned)f2b(ao[rt][co][1] * inv) << 16);
      pk.y = (unsigned)f2b(ao[rt][co][2] * inv) | ((unsigned)f2b(ao[rt][co][3] * inv) << 16);
      *(uint2*)(ctx + (size_t)token * D + h * HD + co * 16 + quad * 4) = pk;
    }
  }
}

// ---------------- output projection: ctx[8192,768] x Wo^T + bias -> fp32 out
__global__ __launch_bounds__(256, 2) void out_gemm(
    const u16* __restrict__ ctx, const u16* __restrict__ wo,
    const float* __restrict__ bias, float* __restrict__ out)
{
  __shared__ __align__(16) u16 As[128 * 40];
  __shared__ __align__(16) u16 Bs[128 * 40];
  const int t = threadIdx.x;
  const int mblk = blockIdx.x, nblk = blockIdx.y;
  const int w = t >> 6, lane = t & 63, quad = lane >> 4, l16 = lane & 15;
  const int wr = w >> 1, wc = w & 1;

  f32x4 acc[4][4];
  #pragma unroll
  for (int i = 0; i < 4; i++)
    #pragma unroll
    for (int j = 0; j < 4; j++) acc[i][j] = (f32x4){0.f, 0.f, 0.f, 0.f};

  const int row0 = t >> 2;
  const int kc   = (t & 3) * 8;
  const u16* gA = ctx + (size_t)(mblk * 128 + row0) * D + kc;
  const u16* gB = wo  + (size_t)(nblk * 128 + row0) * D + kc;

  for (int k0 = 0; k0 < D; k0 += 32) {
    bf16x8 va0 = *(const bf16x8*)(gA + k0);
    bf16x8 va1 = *(const bf16x8*)(gA + (size_t)64 * D + k0);
    bf16x8 vb0 = *(const bf16x8*)(gB + k0);
    bf16x8 vb1 = *(const bf16x8*)(gB + (size_t)64 * D + k0);
    __syncthreads();
    *(bf16x8*)(As + row0 * 40 + kc)        = va0;
    *(bf16x8*)(As + (row0 + 64) * 40 + kc) = va1;
    *(bf16x8*)(Bs + row0 * 40 + kc)        = vb0;
    *(bf16x8*)(Bs + (row0 + 64) * 40 + kc) = vb1;
    __syncthreads();
    bf16x8 af[4], bfr[4];
    #pragma unroll
    for (int mt = 0; mt < 4; mt++) af[mt]  = *(const bf16x8*)(As + (wr * 64 + mt * 16 + l16) * 40 + quad * 8);
    #pragma unroll
    for (int nt = 0; nt < 4; nt++) bfr[nt] = *(const bf16x8*)(Bs + (wc * 64 + nt * 16 + l16) * 40 + quad * 8);
    #pragma unroll
    for (int mt = 0; mt < 4; mt++)
      #pragma unroll
      for (int nt = 0; nt < 4; nt++)
        acc[mt][nt] = MFMA(af[mt], bfr[nt], acc[mt][nt]);
  }

  #pragma unroll
  for (int mt = 0; mt < 4; mt++) {
    int m0 = mblk * 128 + wr * 64 + mt * 16 + quad * 4;
    #pragma unroll
    for (int nt = 0; nt < 4; nt++) {
      int n = nblk * 128 + wc * 64 + nt * 16 + l16;
      float bv = bias[n];
      #pragma unroll
      for (int r = 0; r < 4; r++)
        out[(size_t)(m0 + r) * D + n] = acc[mt][nt][r] + bv;
    }
  }
}

// ---------------- host launch ----------------
extern "C" void kernel_launch(void* const* d_in, const int* in_sizes, int n_in,
                              void* d_out, int out_size, void* d_ws, size_t ws_size,
                              hipStream_t stream) {
  const float* x    = (const float*)d_in[0];
  const float* wq   = (const float*)d_in[1];
  const float* wk   = (const float*)d_in[2];
  const float* wv   = (const float*)d_in[3];
  const float* wo   = (const float*)d_in[4];
  const float* bo   = (const float*)d_in[5];
  float* out = (float*)d_out;

  u16* ws = (u16*)d_ws;
  const size_t NX = (size_t)2 * S * D;      // 6291456
  const size_t NW = (size_t)D * D;          // 589824
  u16* xb  = ws;                // [8192][768]; reused as ctx after qkv_gemm consumes it
  u16* wqb = ws + NX;
  u16* wkb = wqb + NW;
  u16* wvb = wkb + NW;
  u16* wob = wvb + NW;
  u16* Qb  = wob + NW;          // [2][12][4096][64]  (pre-scaled by 0.125*log2e)
  u16* Kb  = Qb + NX;
  u16* Vt  = Kb + NX;           // [2][12][64][4096]
  u16* ctx = xb;

  castk<<<(int)((NX / 4 + 255) / 256), 256, 0, stream>>>(x,  xb,  (int)(NX / 4));
  castk<<<(int)((NW / 4 + 255) / 256), 256, 0, stream>>>(wq, wqb, (int)(NW / 4));
  castk<<<(int)((NW / 4 + 255) / 256), 256, 0, stream>>>(wk, wkb, (int)(NW / 4));
  castk<<<(int)((NW / 4 + 255) / 256), 256, 0, stream>>>(wv, wvb, (int)(NW / 4));
  castk<<<(int)((NW / 4 + 255) / 256), 256, 0, stream>>>(wo, wob, (int)(NW / 4));

  qkv_gemm<<<dim3(64, 6, 3), 256, 0, stream>>>(xb, wqb, wkb, wvb, Qb, Kb, Vt);
  attn<<<dim3(24, 32), 256, 0, stream>>>(Qb, Kb, Vt, ctx);
  out_gemm<<<dim3(64, 6), 256, 0, stream>>>(ctx, wob, bo, out);
}